// Round 4
// baseline (15905.632 us; speedup 1.0000x reference)
//
#include <hip/hip_runtime.h>

typedef _Float16 f16;
typedef _Float16 f16x8 __attribute__((ext_vector_type(8)));
typedef float f32x4 __attribute__((ext_vector_type(4)));
typedef unsigned int u32;
typedef u32 u32x4 __attribute__((ext_vector_type(4)));

#define SEQ 2048
#define NBAT 64
#define NH 512
#define OUT0_ELEMS (SEQ * NBAT * NH)

#define AGENT __HIP_MEMORY_SCOPE_AGENT
#define RLX __ATOMIC_RELAXED

// ws layout (memset [0,8192) each launch; rings are flag-gated, not cleared):
//   [0,64)        gab (global abort)
//   [64,4160)     flags: per cluster c (512B): flags0[32] @ +0 (stride 8B),
//                 flags1[32] @ +256
//   [8192,...)    ring0: per cluster 8 slots x 8192B ([8 b][512 f] f16)
//   [532480,...)  ring1: per cluster 2 slots x 8192B
#define WS_FLAGS 64
#define WS_RING0 8192
#define WS_RING1 (8192 + 8 * 65536)

#define MFMA16(a, b, c) __builtin_amdgcn_mfma_f32_16x16x32_f16((a), (b), (c), 0, 0, 0)

#define WAIT_VM0()                                   \
  do {                                               \
    asm volatile("s_waitcnt vmcnt(0)" ::: "memory"); \
    __builtin_amdgcn_sched_barrier(0);               \
  } while (0)

// ---- agent-scope (R1-proven) memory ops: sc0 sc1 ----
__device__ __forceinline__ u32x4 ld_sc(const void* p) {
  u32x4 d;
  asm volatile("global_load_dwordx4 %0, %1, off sc0 sc1" : "=v"(d) : "v"(p) : "memory");
  return d;
}
__device__ __forceinline__ void st_sc_u32(void* p, u32 v) {
  asm volatile("global_store_dword %0, %1, off sc0 sc1" ::"v"(p), "v"(v) : "memory");
}
__device__ __forceinline__ void st_sc_u16(void* p, u32 v) {
  asm volatile("global_store_short %0, %1, off sc0 sc1" ::"v"(p), "v"(v) : "memory");
}
__device__ __forceinline__ u32 poll_sc(const void* p) {
  u32 d;
  asm volatile("global_load_dword %0, %1, off sc0 sc1\n\ts_waitcnt vmcnt(0)"
               : "=v"(d) : "v"(p) : "memory");
  return d;
}

__device__ __forceinline__ f16x8 asf(u32x4 v) {
  union { u32x4 u; f16x8 h; } x;
  x.u = v;
  return x.h;
}
__device__ __forceinline__ f16x8 cvt2(float4 a, float4 b) {
  f16x8 v;
  v[0] = (f16)a.x; v[1] = (f16)a.y; v[2] = (f16)a.z; v[3] = (f16)a.w;
  v[4] = (f16)b.x; v[5] = (f16)b.y; v[6] = (f16)b.z; v[7] = (f16)b.w;
  return v;
}
__device__ __forceinline__ f16x8 ldcvt8(const float* p) {
  float4 a = *(const float4*)p;
  float4 b = *(const float4*)(p + 4);
  return cvt2(a, b);
}
__device__ __forceinline__ u32 h2b(float v) {
  union { f16 h[2]; u32 u; } x;
  x.u = 0;
  x.h[0] = (f16)v;
  return x.u;
}

// lanes<32 poll flags0[lane] >= tgtA ; lanes>=32 poll flags1[lane-32] >= tgtB
__device__ __forceinline__ bool spin2(const char* fb, u32 tgtA, u32 tgtB, u32* gab) {
  const int lane = threadIdx.x & 63;
  const char* p = fb + lane * 8;
  const u32 tgt = (lane < 32) ? tgtA : tgtB;
  int it = 0;
  for (;;) {
    u32 v = poll_sc(p);
    if (__all((int)(v >= tgt))) return true;
    if (((++it) & 63) == 0) {
      if (__hip_atomic_load(gab, RLX, AGENT) || it > (1 << 20)) {
        __hip_atomic_store(gab, 1u, RLX, AGENT);
        return false;
      }
    }
  }
}

// grid = 128 WGs x 256 thr (4 waves). Roles from bid: cluster c = bid>>4
// (batches 8c..8c+7), layer = (bid>>3)&1, slice r = bid&7 (64 features).
__global__ __launch_bounds__(256, 1) void rnn_pers(
    const float* __restrict__ x, const float* __restrict__ hx,
    const float* __restrict__ w_ih, const float* __restrict__ w_hh,
    const float* __restrict__ b_ih, const float* __restrict__ b_hh,
    float* __restrict__ out, char* __restrict__ ws) {
  const int tid = threadIdx.x;
  const int lane = tid & 63;
  const int wv = tid >> 6;
  const int bid = blockIdx.x;
  const int c = bid >> 4;
  const int layer = (bid >> 3) & 1;
  const int r = bid & 7;

  const int mrow = lane & 15;     // A-row / D-col
  const int kgrp = lane >> 4;     // 0..3
  const int jl = wv * 16 + mrow;  // feature within 64-slice
  const int jg = r * 64 + jl;     // global feature
  const int brow = mrow & 7;      // batch row (8 batches, rows 8-15 dup)
  const int gb = c * 8;
  const int aoff = brow * 1024 + kgrp * 16;
  const int fq = (r * 4 + wv) * 8;  // per-wave flag slot

  u32* gab = (u32*)ws;
  char* fb = ws + WS_FLAGS + c * 512;
  char* ring0 = ws + WS_RING0 + (size_t)c * 65536;
  char* ring1 = ws + WS_RING1 + (size_t)c * 16384;

  // ---- persistent weight fragments in VGPRs ----
  f16x8 wif[16], whf[16];
  {
    const float* s1 = w_ih + ((size_t)layer * NH + jg) * NH + kgrp * 8;
    const float* s2 = w_hh + ((size_t)layer * NH + jg) * NH + kgrp * 8;
#pragma unroll
    for (int kk = 0; kk < 16; ++kk) wif[kk] = ldcvt8(s1 + kk * 32);
#pragma unroll
    for (int kk = 0; kk < 16; ++kk) whf[kk] = ldcvt8(s2 + kk * 32);
  }
  const float bias = b_ih[layer * NH + jg] + b_hh[layer * NH + jg];
  const f32x4 bias4 = {bias, bias, bias, bias};
  const f32x4 zero4 = {0.f, 0.f, 0.f, 0.f};

  if (layer == 0) {
    // ============================ LAYER 0 ============================
    f32x4 xc0 = bias4, xc1 = zero4, xc2 = zero4, xc3 = zero4;
    {  // input projection of x[0] (direct f32)
      const float* xb = x + (size_t)(gb + brow) * NH + kgrp * 8;
#pragma unroll
      for (int kk = 0; kk < 16; kk += 4) {
        xc0 = MFMA16(ldcvt8(xb + (kk + 0) * 32), wif[kk + 0], xc0);
        xc1 = MFMA16(ldcvt8(xb + (kk + 1) * 32), wif[kk + 1], xc1);
        xc2 = MFMA16(ldcvt8(xb + (kk + 2) * 32), wif[kk + 2], xc2);
        xc3 = MFMA16(ldcvt8(xb + (kk + 3) * 32), wif[kk + 3], xc3);
      }
    }
    float4 xpa[16], xpb[16];  // parked x[t+1] (f32)
    u32x4 gf[16];
    for (int t = 0; t < SEQ; ++t) {
      f32x4 c0 = xc0, c1 = xc1, c2 = xc2, c3 = xc3;
      if (t == 0) {
        {  // prefetch x[1]
          const float* xb = x + ((size_t)NBAT + gb + brow) * NH + kgrp * 8;
#pragma unroll
          for (int kk = 0; kk < 16; ++kk) {
            xpa[kk] = *(const float4*)(xb + kk * 32);
            xpb[kk] = *(const float4*)(xb + kk * 32 + 4);
          }
        }
        const float* hb = hx + (size_t)(gb + brow) * NH + kgrp * 8;
#pragma unroll
        for (int kk = 0; kk < 16; kk += 4) {
          c0 = MFMA16(ldcvt8(hb + (kk + 0) * 32), whf[kk + 0], c0);
          c1 = MFMA16(ldcvt8(hb + (kk + 1) * 32), whf[kk + 1], c1);
          c2 = MFMA16(ldcvt8(hb + (kk + 2) * 32), whf[kk + 2], c2);
          c3 = MFMA16(ldcvt8(hb + (kk + 3) * 32), whf[kk + 3], c3);
        }
      } else {
        // flags0>=t : h0[t-1] ready ; flags1>=t-7 : ring0 slot t&7 reusable
        if (!spin2(fb, (u32)t, (t >= 7) ? (u32)(t - 7) : 0u, gab)) return;
        const char* hb = ring0 + (size_t)((t - 1) & 7) * 8192 + aoff;
#pragma unroll
        for (int kk = 0; kk < 16; ++kk) gf[kk] = ld_sc(hb + kk * 64);
        if (t < SEQ - 1) {  // x[t+1] prefetch rides the same latency window
          const float* xb = x + ((size_t)(t + 1) * NBAT + gb + brow) * NH + kgrp * 8;
#pragma unroll
          for (int kk = 0; kk < 16; ++kk) {
            xpa[kk] = *(const float4*)(xb + kk * 32);
            xpb[kk] = *(const float4*)(xb + kk * 32 + 4);
          }
        }
        WAIT_VM0();
#pragma unroll
        for (int kk = 0; kk < 16; kk += 4) {
          c0 = MFMA16(asf(gf[kk + 0]), whf[kk + 0], c0);
          c1 = MFMA16(asf(gf[kk + 1]), whf[kk + 1], c1);
          c2 = MFMA16(asf(gf[kk + 2]), whf[kk + 2], c2);
          c3 = MFMA16(asf(gf[kk + 3]), whf[kk + 3], c3);
        }
      }
      f32x4 acc = (c0 + c1) + (c2 + c3);
      float hv0 = fmaxf(acc[0], 0.f), hv1 = fmaxf(acc[1], 0.f);
      float hv2 = fmaxf(acc[2], 0.f), hv3 = fmaxf(acc[3], 0.f);
      if (t == SEQ - 1 && kgrp < 2) {  // h_final layer 0
        float* hfo = out + OUT0_ELEMS + (size_t)gb * NH + jg;
        hfo[(size_t)(4 * kgrp + 0) * NH] = hv0;
        hfo[(size_t)(4 * kgrp + 1) * NH] = hv1;
        hfo[(size_t)(4 * kgrp + 2) * NH] = hv2;
        hfo[(size_t)(4 * kgrp + 3) * NH] = hv3;
      }
      if (kgrp < 2) {  // h0[t] -> ring0 slot t&7 (batch 4*kgrp+i, feature jg)
        char* rb = ring0 + (size_t)(t & 7) * 8192 + jg * 2;
        st_sc_u16(rb + (4 * kgrp + 0) * 1024, h2b(hv0));
        st_sc_u16(rb + (4 * kgrp + 1) * 1024, h2b(hv1));
        st_sc_u16(rb + (4 * kgrp + 2) * 1024, h2b(hv2));
        st_sc_u16(rb + (4 * kgrp + 3) * 1024, h2b(hv3));
      }
      WAIT_VM0();
      if (lane == 0) st_sc_u32(fb + fq, (u32)(t + 1));
      if (t < SEQ - 1) {  // off-critical-path: xacc(t+1) from parked x
        xc0 = bias4; xc1 = zero4; xc2 = zero4; xc3 = zero4;
#pragma unroll
        for (int kk = 0; kk < 16; kk += 4) {
          xc0 = MFMA16(cvt2(xpa[kk + 0], xpb[kk + 0]), wif[kk + 0], xc0);
          xc1 = MFMA16(cvt2(xpa[kk + 1], xpb[kk + 1]), wif[kk + 1], xc1);
          xc2 = MFMA16(cvt2(xpa[kk + 2], xpb[kk + 2]), wif[kk + 2], xc2);
          xc3 = MFMA16(cvt2(xpa[kk + 3], xpb[kk + 3]), wif[kk + 3], xc3);
        }
      }
    }
  } else {
    // ============================ LAYER 1 ============================
    u32x4 gf[16], g2[16];
    f32x4 xc0, xc1, xc2, xc3;
    if (!spin2(fb, 1u, 0u, gab)) return;
    {  // xacc = bias + Wi1 @ h0[0]
      const char* hb = ring0 + aoff;  // slot 0
#pragma unroll
      for (int kk = 0; kk < 16; ++kk) g2[kk] = ld_sc(hb + kk * 64);
      WAIT_VM0();
      xc0 = bias4; xc1 = zero4; xc2 = zero4; xc3 = zero4;
#pragma unroll
      for (int kk = 0; kk < 16; kk += 4) {
        xc0 = MFMA16(asf(g2[kk + 0]), wif[kk + 0], xc0);
        xc1 = MFMA16(asf(g2[kk + 1]), wif[kk + 1], xc1);
        xc2 = MFMA16(asf(g2[kk + 2]), wif[kk + 2], xc2);
        xc3 = MFMA16(asf(g2[kk + 3]), wif[kk + 3], xc3);
      }
    }
    for (int t = 0; t < SEQ; ++t) {
      // flags0>=t+2 : h0[t+1] ready (for the tail) ; flags1>=t : h1[t-1] ready
      u32 tgtA = (t < SEQ - 1) ? (u32)(t + 2) : (u32)SEQ;
      if (!spin2(fb, tgtA, (u32)t, gab)) return;
      f32x4 c0 = xc0, c1 = xc1, c2 = xc2, c3 = xc3;
      if (t < SEQ - 1) {  // issue h0[t+1] gather early; parked in g2
        const char* hb = ring0 + (size_t)((t + 1) & 7) * 8192 + aoff;
#pragma unroll
        for (int kk = 0; kk < 16; ++kk) g2[kk] = ld_sc(hb + kk * 64);
      }
      if (t == 0) {
        const float* hb = hx + (size_t)(NBAT + gb + brow) * NH + kgrp * 8;
#pragma unroll
        for (int kk = 0; kk < 16; kk += 4) {
          c0 = MFMA16(ldcvt8(hb + (kk + 0) * 32), whf[kk + 0], c0);
          c1 = MFMA16(ldcvt8(hb + (kk + 1) * 32), whf[kk + 1], c1);
          c2 = MFMA16(ldcvt8(hb + (kk + 2) * 32), whf[kk + 2], c2);
          c3 = MFMA16(ldcvt8(hb + (kk + 3) * 32), whf[kk + 3], c3);
        }
      } else {
        const char* hb = ring1 + (size_t)((t - 1) & 1) * 8192 + aoff;
#pragma unroll
        for (int kk = 0; kk < 16; ++kk) gf[kk] = ld_sc(hb + kk * 64);
        WAIT_VM0();
#pragma unroll
        for (int kk = 0; kk < 16; kk += 4) {
          c0 = MFMA16(asf(gf[kk + 0]), whf[kk + 0], c0);
          c1 = MFMA16(asf(gf[kk + 1]), whf[kk + 1], c1);
          c2 = MFMA16(asf(gf[kk + 2]), whf[kk + 2], c2);
          c3 = MFMA16(asf(gf[kk + 3]), whf[kk + 3], c3);
        }
      }
      f32x4 acc = (c0 + c1) + (c2 + c3);
      float hv0 = fmaxf(acc[0], 0.f), hv1 = fmaxf(acc[1], 0.f);
      float hv2 = fmaxf(acc[2], 0.f), hv3 = fmaxf(acc[3], 0.f);
      if (t == SEQ - 1 && kgrp < 2) {  // h_final layer 1
        float* hfo = out + OUT0_ELEMS + (size_t)(NBAT + gb) * NH + jg;
        hfo[(size_t)(4 * kgrp + 0) * NH] = hv0;
        hfo[(size_t)(4 * kgrp + 1) * NH] = hv1;
        hfo[(size_t)(4 * kgrp + 2) * NH] = hv2;
        hfo[(size_t)(4 * kgrp + 3) * NH] = hv3;
      }
      if (kgrp < 2) {  // h1[t] -> ring1 slot t&1
        char* rb = ring1 + (size_t)(t & 1) * 8192 + jg * 2;
        st_sc_u16(rb + (4 * kgrp + 0) * 1024, h2b(hv0));
        st_sc_u16(rb + (4 * kgrp + 1) * 1024, h2b(hv1));
        st_sc_u16(rb + (4 * kgrp + 2) * 1024, h2b(hv2));
        st_sc_u16(rb + (4 * kgrp + 3) * 1024, h2b(hv3));
      }
      WAIT_VM0();  // also drains the g2 gather
      if (lane == 0) st_sc_u32(fb + 256 + fq, (u32)(t + 1));
      if (kgrp < 2) {  // final output (plain stores, off critical path)
        float* ob = out + ((size_t)t * NBAT + gb) * NH + jg;
        ob[(size_t)(4 * kgrp + 0) * NH] = hv0;
        ob[(size_t)(4 * kgrp + 1) * NH] = hv1;
        ob[(size_t)(4 * kgrp + 2) * NH] = hv2;
        ob[(size_t)(4 * kgrp + 3) * NH] = hv3;
      }
      if (t < SEQ - 1) {  // xacc(t+1) = bias + Wi1 @ h0[t+1] (parked g2)
        xc0 = bias4; xc1 = zero4; xc2 = zero4; xc3 = zero4;
#pragma unroll
        for (int kk = 0; kk < 16; kk += 4) {
          xc0 = MFMA16(asf(g2[kk + 0]), wif[kk + 0], xc0);
          xc1 = MFMA16(asf(g2[kk + 1]), wif[kk + 1], xc1);
          xc2 = MFMA16(asf(g2[kk + 2]), wif[kk + 2], xc2);
          xc3 = MFMA16(asf(g2[kk + 3]), wif[kk + 3], xc3);
        }
      }
    }
  }
}

extern "C" void kernel_launch(void* const* d_in, const int* in_sizes, int n_in,
                              void* d_out, int out_size, void* d_ws, size_t ws_size,
                              hipStream_t stream) {
  (void)in_sizes; (void)n_in; (void)out_size; (void)ws_size;
  const float* x = (const float*)d_in[0];
  const float* hx = (const float*)d_in[1];
  const float* w_ih = (const float*)d_in[2];
  const float* w_hh = (const float*)d_in[3];
  const float* b_ih = (const float*)d_in[4];
  const float* b_hh = (const float*)d_in[5];
  float* out = (float*)d_out;
  char* ws = (char*)d_ws;

  // zero gab + all flags (agent-coherent region); rings are flag-gated
  (void)hipMemsetAsync(d_ws, 0, 8192, stream);
  rnn_pers<<<dim3(128), dim3(256), 0, stream>>>(x, hx, w_ih, w_hh, b_ih, b_hh, out, ws);
}

// Round 6
// 12435.328 us; speedup vs baseline: 1.2791x; 1.2791x over previous
//
#include <hip/hip_runtime.h>

typedef _Float16 f16;
typedef _Float16 f16x8 __attribute__((ext_vector_type(8)));
typedef float f32x4 __attribute__((ext_vector_type(4)));
typedef unsigned int u32;
typedef u32 u32x4 __attribute__((ext_vector_type(4)));

#define SEQ 2048
#define NBAT 64
#define NH 512
#define OUT0_ELEMS (SEQ * NBAT * NH)
#define TSLICE (NBAT * NH)  // 32768 f32 per t-slice

#define AGENT __HIP_MEMORY_SCOPE_AGENT
#define RLX __ATOMIC_RELAXED

// ws layout (memset [0,8192) each launch; rings are flag-gated, not cleared):
//   [0,64)      gab
//   64+c*512    flags0[32] (8B stride) @+0, flags1[32] @+256
//   8192        ring0: + c*65536, 8 slots x 8192B ([8 b][512 f] f16)
//   532480      ring1: + c*16384, 2 slots x 8192B
#define WS_FLAGS 64
#define WS_RING0 8192
#define WS_RING1 (8192 + 8 * 65536)

#define MFMA16(a, b, c) __builtin_amdgcn_mfma_f32_16x16x32_f16((a), (b), (c), 0, 0, 0)

#define WAIT_VM0()                                   \
  do {                                               \
    asm volatile("s_waitcnt vmcnt(0)" ::: "memory"); \
    __builtin_amdgcn_sched_barrier(0);               \
  } while (0)

// ---- agent-scope (R1/R4-proven) memory ops: sc0 sc1 ----
__device__ __forceinline__ u32x4 ld_sc(const void* p) {
  u32x4 d;
  asm volatile("global_load_dwordx4 %0, %1, off sc0 sc1" : "=v"(d) : "v"(p) : "memory");
  return d;
}
__device__ __forceinline__ void st_sc_u32(void* p, u32 v) {
  asm volatile("global_store_dword %0, %1, off sc0 sc1" ::"v"(p), "v"(v) : "memory");
}
__device__ __forceinline__ void st_sc_u16(void* p, u32 v) {
  asm volatile("global_store_short %0, %1, off sc0 sc1" ::"v"(p), "v"(v) : "memory");
}
__device__ __forceinline__ u32 poll_sc(const void* p) {
  u32 d;
  asm volatile("global_load_dword %0, %1, off sc0 sc1\n\ts_waitcnt vmcnt(0)"
               : "=v"(d) : "v"(p) : "memory");
  return d;
}

__device__ __forceinline__ f16x8 asf(u32x4 v) {
  union { u32x4 u; f16x8 h; } x;
  x.u = v;
  return x.h;
}
__device__ __forceinline__ f16x8 cvt2(float4 a, float4 b) {
  f16x8 v;
  v[0] = (f16)a.x; v[1] = (f16)a.y; v[2] = (f16)a.z; v[3] = (f16)a.w;
  v[4] = (f16)b.x; v[5] = (f16)b.y; v[6] = (f16)b.z; v[7] = (f16)b.w;
  return v;
}
__device__ __forceinline__ f16x8 ldcvt8(const float* p) {
  float4 a = *(const float4*)p;
  float4 b = *(const float4*)(p + 4);
  return cvt2(a, b);
}
__device__ __forceinline__ u32 h2b(float v) {
  union { f16 h[2]; u32 u; } x;
  x.u = 0;
  x.h[0] = (f16)v;
  return x.u;
}

// lanes<32 poll flags0[lane] >= tgtA ; lanes>=32 poll flags1[lane-32] >= tgtB
__device__ __forceinline__ bool spin2(const char* fb, u32 tgtA, u32 tgtB, u32* gab) {
  const int lane = threadIdx.x & 63;
  const char* p = fb + lane * 8;
  const u32 tgt = (lane < 32) ? tgtA : tgtB;
  int it = 0;
  for (;;) {
    u32 v = poll_sc(p);
    if (__all((int)(v >= tgt))) return true;
    if (((++it) & 63) == 0) {
      if (__hip_atomic_load(gab, RLX, AGENT) || it > (1 << 20)) {
        __hip_atomic_store(gab, 1u, RLX, AGENT);
        return false;
      }
    }
  }
}

// ============ kernel 1: pre0[t] = b_ih0 + b_hh0 + Wi0 @ x[t], D-frag layout ===
// Stored into out[t]'s slice (dead until L1 overwrites; L0 reads strictly ahead).
// grid 2048 = c(8) x r(8) x ch(32); block 256 (4 waves). No inter-WG sync.
__global__ __launch_bounds__(256) void pre0_gemm(
    const float* __restrict__ x, const float* __restrict__ w_ih,
    const float* __restrict__ b_ih, const float* __restrict__ b_hh,
    float* __restrict__ out) {
  __shared__ __align__(16) char XT[8192];  // x[t] slice, f16, XOR-swizzled
  const int tid = threadIdx.x;
  const int lane = tid & 63;
  const int wv = tid >> 6;
  const int bid = blockIdx.x;
  const int c = bid >> 8;
  const int r = (bid >> 5) & 7;
  const int ch = bid & 31;
  const int gb = c * 8;
  const int mrow = lane & 15;
  const int kgrp = lane >> 4;
  const int jl = wv * 16 + mrow;
  const int jg = r * 64 + jl;
  const int brow = mrow & 7;

  f16x8 wif[16];
  {
    const float* s1 = w_ih + (size_t)jg * NH + kgrp * 8;
#pragma unroll
    for (int kk = 0; kk < 16; ++kk) wif[kk] = ldcvt8(s1 + kk * 32);
  }
  const float bias = b_ih[jg] + b_hh[jg];
  const f32x4 bias4 = {bias, bias, bias, bias};
  const f32x4 zero4 = {0.f, 0.f, 0.f, 0.f};

  const int sb = (tid * 16) >> 9;   // staged batch row
  const int sk = (tid * 16) & 511;  // staged k start (16 f32)

#define XA(kk) \
  (*(const f16x8*)(XT + brow * 1024 + ((((kk) * 64) + kgrp * 16) ^ (brow << 4))))

  for (int ti = 0; ti < 64; ++ti) {
    const int t = ch * 64 + ti;
    {  // stage x[t] 8-batch slice -> f16 LDS (swizzled)
      const float* sp = x + ((size_t)t * NBAT + gb + sb) * NH + sk;
      float4 a0 = *(const float4*)(sp);
      float4 a1 = *(const float4*)(sp + 4);
      float4 a2 = *(const float4*)(sp + 8);
      float4 a3 = *(const float4*)(sp + 12);
      union { f16x8 h; u32x4 u; } v0, v1;
      v0.h = cvt2(a0, a1);
      v1.h = cvt2(a2, a3);
      *(u32x4*)(XT + sb * 1024 + ((sk * 2) ^ (sb << 4))) = v0.u;
      *(u32x4*)(XT + sb * 1024 + (((sk + 8) * 2) ^ (sb << 4))) = v1.u;
    }
    __syncthreads();
    f32x4 c0 = bias4, c1 = zero4, c2 = zero4, c3 = zero4;
#pragma unroll
    for (int kk = 0; kk < 16; kk += 4) {
      c0 = MFMA16(XA(kk + 0), wif[kk + 0], c0);
      c1 = MFMA16(XA(kk + 1), wif[kk + 1], c1);
      c2 = MFMA16(XA(kk + 2), wif[kk + 2], c2);
      c3 = MFMA16(XA(kk + 3), wif[kk + 3], c3);
    }
    f32x4 acc = (c0 + c1) + (c2 + c3);
    if (kgrp < 2) {
      const int fi = ((c * 8 + r) * 4 + wv) * 32 + kgrp * 16 + mrow;
      *(f32x4*)(out + (size_t)t * TSLICE + fi * 4) = acc;
    }
    __syncthreads();
  }
#undef XA
}

// ================== kernel 2: persistent recurrence (R4 template) ==================
// grid = 128 WGs x 256 thr. c = bid>>4, layer = (bid>>3)&1, r = bid&7.
__global__ __launch_bounds__(256, 1) void rnn_pers(
    const float* __restrict__ x, const float* __restrict__ hx,
    const float* __restrict__ w_ih, const float* __restrict__ w_hh,
    const float* __restrict__ b_ih, const float* __restrict__ b_hh,
    float* __restrict__ out, char* __restrict__ ws) {
  const int tid = threadIdx.x;
  const int lane = tid & 63;
  const int wv = tid >> 6;
  const int bid = blockIdx.x;
  const int c = bid >> 4;
  const int layer = (bid >> 3) & 1;
  const int r = bid & 7;

  const int mrow = lane & 15;
  const int kgrp = lane >> 4;
  const int jl = wv * 16 + mrow;
  const int jg = r * 64 + jl;
  const int brow = mrow & 7;
  const int gb = c * 8;
  const int aoff = brow * 1024 + kgrp * 16;
  const int fq = (r * 4 + wv) * 8;

  u32* gab = (u32*)ws;
  char* fb = ws + WS_FLAGS + c * 512;
  char* ring0 = ws + WS_RING0 + (size_t)c * 65536;
  char* ring1 = ws + WS_RING1 + (size_t)c * 16384;

  f16x8 whf[16];
  {
    const float* s2 = w_hh + ((size_t)layer * NH + jg) * NH + kgrp * 8;
#pragma unroll
    for (int kk = 0; kk < 16; ++kk) whf[kk] = ldcvt8(s2 + kk * 32);
  }
  const f32x4 zero4 = {0.f, 0.f, 0.f, 0.f};

  if (layer == 0) {
    // ============================ LAYER 0 ============================
    // pre0 fragment address for this lane (kgrp>=2 reads the kgrp&1 copy)
    const size_t fi0 =
        (size_t)(((c * 8 + r) * 4 + wv) * 32 + (kgrp & 1) * 16 + mrow) * 4;
    const float* pf = out + fi0;
    u32x4 gf[16];
    f32x4 xpA = *(const f32x4*)(pf);                       // pre0[0]
    f32x4 xpB = *(const f32x4*)(pf + (size_t)1 * TSLICE);  // pre0[1]
    f32x4 xpC;
    for (int t = 0; t < SEQ; ++t) {
      f32x4 c0 = xpA, c1 = zero4, c2 = zero4, c3 = zero4;
      if (t == 0) {
        xpC = *(const f32x4*)(pf + (size_t)2 * TSLICE);
        const float* hb = hx + (size_t)(gb + brow) * NH + kgrp * 8;
#pragma unroll
        for (int kk = 0; kk < 16; kk += 4) {
          c0 = MFMA16(ldcvt8(hb + (kk + 0) * 32), whf[kk + 0], c0);
          c1 = MFMA16(ldcvt8(hb + (kk + 1) * 32), whf[kk + 1], c1);
          c2 = MFMA16(ldcvt8(hb + (kk + 2) * 32), whf[kk + 2], c2);
          c3 = MFMA16(ldcvt8(hb + (kk + 3) * 32), whf[kk + 3], c3);
        }
      } else {
        // flags0>=t : h0[t-1] ready ; flags1>=t-7 : ring0 slot t&7 reusable
        if (!spin2(fb, (u32)t, (t >= 7) ? (u32)(t - 7) : 0u, gab)) return;
        const char* hb = ring0 + (size_t)((t - 1) & 7) * 8192 + aoff;
#pragma unroll
        for (int kk = 0; kk < 16; ++kk) gf[kk] = ld_sc(hb + kk * 64);
        {  // prefetch pre0[t+2] in the same latency window (L3/HBM)
          int tp = (t + 2 < SEQ) ? (t + 2) : (SEQ - 1);
          xpC = *(const f32x4*)(pf + (size_t)tp * TSLICE);
        }
        WAIT_VM0();
#pragma unroll
        for (int kk = 0; kk < 16; kk += 4) {
          c0 = MFMA16(asf(gf[kk + 0]), whf[kk + 0], c0);
          c1 = MFMA16(asf(gf[kk + 1]), whf[kk + 1], c1);
          c2 = MFMA16(asf(gf[kk + 2]), whf[kk + 2], c2);
          c3 = MFMA16(asf(gf[kk + 3]), whf[kk + 3], c3);
        }
      }
      f32x4 acc = (c0 + c1) + (c2 + c3);
      float hv0 = fmaxf(acc[0], 0.f), hv1 = fmaxf(acc[1], 0.f);
      float hv2 = fmaxf(acc[2], 0.f), hv3 = fmaxf(acc[3], 0.f);
      if (t == SEQ - 1 && kgrp < 2) {  // h_final layer 0
        float* hfo = out + OUT0_ELEMS + (size_t)gb * NH + jg;
        hfo[(size_t)(4 * kgrp + 0) * NH] = hv0;
        hfo[(size_t)(4 * kgrp + 1) * NH] = hv1;
        hfo[(size_t)(4 * kgrp + 2) * NH] = hv2;
        hfo[(size_t)(4 * kgrp + 3) * NH] = hv3;
      }
      if (kgrp < 2) {  // h0[t] -> ring0 slot t&7
        char* rb = ring0 + (size_t)(t & 7) * 8192 + jg * 2;
        st_sc_u16(rb + (4 * kgrp + 0) * 1024, h2b(hv0));
        st_sc_u16(rb + (4 * kgrp + 1) * 1024, h2b(hv1));
        st_sc_u16(rb + (4 * kgrp + 2) * 1024, h2b(hv2));
        st_sc_u16(rb + (4 * kgrp + 3) * 1024, h2b(hv3));
      }
      WAIT_VM0();
      if (lane == 0) st_sc_u32(fb + fq, (u32)(t + 1));
      xpA = xpB;
      xpB = xpC;
    }
  } else {
    // ============================ LAYER 1 ============================
    f16x8 wif[16];
    {
      const float* s1 = w_ih + ((size_t)NH + jg) * NH + kgrp * 8;
#pragma unroll
      for (int kk = 0; kk < 16; ++kk) wif[kk] = ldcvt8(s1 + kk * 32);
    }
    const float bias = b_ih[NH + jg] + b_hh[NH + jg];
    const f32x4 bias4 = {bias, bias, bias, bias};
    u32x4 gf[16], g2[16];
    f32x4 xc0, xc1, xc2, xc3;
    if (!spin2(fb, 1u, 0u, gab)) return;
    {  // xacc = bias + Wi1 @ h0[0]
      const char* hb = ring0 + aoff;  // slot 0
#pragma unroll
      for (int kk = 0; kk < 16; ++kk) g2[kk] = ld_sc(hb + kk * 64);
      WAIT_VM0();
      xc0 = bias4; xc1 = zero4; xc2 = zero4; xc3 = zero4;
#pragma unroll
      for (int kk = 0; kk < 16; kk += 4) {
        xc0 = MFMA16(asf(g2[kk + 0]), wif[kk + 0], xc0);
        xc1 = MFMA16(asf(g2[kk + 1]), wif[kk + 1], xc1);
        xc2 = MFMA16(asf(g2[kk + 2]), wif[kk + 2], xc2);
        xc3 = MFMA16(asf(g2[kk + 3]), wif[kk + 3], xc3);
      }
    }
    for (int t = 0; t < SEQ; ++t) {
      // flags0>=t+2 : h0[t+1] ready (tail) ; flags1>=t : h1[t-1] ready
      u32 tgtA = (t < SEQ - 1) ? (u32)(t + 2) : (u32)SEQ;
      if (!spin2(fb, tgtA, (u32)t, gab)) return;
      f32x4 c0 = xc0, c1 = xc1, c2 = xc2, c3 = xc3;
      if (t < SEQ - 1) {  // issue h0[t+1] gather early; parked in g2
        const char* hb = ring0 + (size_t)((t + 1) & 7) * 8192 + aoff;
#pragma unroll
        for (int kk = 0; kk < 16; ++kk) g2[kk] = ld_sc(hb + kk * 64);
      }
      if (t == 0) {
        const float* hb = hx + (size_t)(NBAT + gb + brow) * NH + kgrp * 8;
#pragma unroll
        for (int kk = 0; kk < 16; kk += 4) {
          c0 = MFMA16(ldcvt8(hb + (kk + 0) * 32), whf[kk + 0], c0);
          c1 = MFMA16(ldcvt8(hb + (kk + 1) * 32), whf[kk + 1], c1);
          c2 = MFMA16(ldcvt8(hb + (kk + 2) * 32), whf[kk + 2], c2);
          c3 = MFMA16(ldcvt8(hb + (kk + 3) * 32), whf[kk + 3], c3);
        }
      } else {
        const char* hb = ring1 + (size_t)((t - 1) & 1) * 8192 + aoff;
#pragma unroll
        for (int kk = 0; kk < 16; ++kk) gf[kk] = ld_sc(hb + kk * 64);
        WAIT_VM0();
#pragma unroll
        for (int kk = 0; kk < 16; kk += 4) {
          c0 = MFMA16(asf(gf[kk + 0]), whf[kk + 0], c0);
          c1 = MFMA16(asf(gf[kk + 1]), whf[kk + 1], c1);
          c2 = MFMA16(asf(gf[kk + 2]), whf[kk + 2], c2);
          c3 = MFMA16(asf(gf[kk + 3]), whf[kk + 3], c3);
        }
      }
      f32x4 acc = (c0 + c1) + (c2 + c3);
      float hv0 = fmaxf(acc[0], 0.f), hv1 = fmaxf(acc[1], 0.f);
      float hv2 = fmaxf(acc[2], 0.f), hv3 = fmaxf(acc[3], 0.f);
      if (t == SEQ - 1 && kgrp < 2) {  // h_final layer 1
        float* hfo = out + OUT0_ELEMS + (size_t)(NBAT + gb) * NH + jg;
        hfo[(size_t)(4 * kgrp + 0) * NH] = hv0;
        hfo[(size_t)(4 * kgrp + 1) * NH] = hv1;
        hfo[(size_t)(4 * kgrp + 2) * NH] = hv2;
        hfo[(size_t)(4 * kgrp + 3) * NH] = hv3;
      }
      if (kgrp < 2) {
        char* rb = ring1 + (size_t)(t & 1) * 8192 + jg * 2;
        st_sc_u16(rb + (4 * kgrp + 0) * 1024, h2b(hv0));
        st_sc_u16(rb + (4 * kgrp + 1) * 1024, h2b(hv1));
        st_sc_u16(rb + (4 * kgrp + 2) * 1024, h2b(hv2));
        st_sc_u16(rb + (4 * kgrp + 3) * 1024, h2b(hv3));
        // final output: issued BEFORE the drain so its (L2) acks share it
        float* ob = out + ((size_t)t * NBAT + gb) * NH + jg;
        ob[(size_t)(4 * kgrp + 0) * NH] = hv0;
        ob[(size_t)(4 * kgrp + 1) * NH] = hv1;
        ob[(size_t)(4 * kgrp + 2) * NH] = hv2;
        ob[(size_t)(4 * kgrp + 3) * NH] = hv3;
      }
      WAIT_VM0();  // drains ring1 st + out st + g2 gather
      if (lane == 0) st_sc_u32(fb + 256 + fq, (u32)(t + 1));
      if (t < SEQ - 1) {  // xacc(t+1) = bias + Wi1 @ h0[t+1] (parked g2)
        xc0 = bias4; xc1 = zero4; xc2 = zero4; xc3 = zero4;
#pragma unroll
        for (int kk = 0; kk < 16; kk += 4) {
          xc0 = MFMA16(asf(g2[kk + 0]), wif[kk + 0], xc0);
          xc1 = MFMA16(asf(g2[kk + 1]), wif[kk + 1], xc1);
          xc2 = MFMA16(asf(g2[kk + 2]), wif[kk + 2], xc2);
          xc3 = MFMA16(asf(g2[kk + 3]), wif[kk + 3], xc3);
        }
      }
    }
  }
}

extern "C" void kernel_launch(void* const* d_in, const int* in_sizes, int n_in,
                              void* d_out, int out_size, void* d_ws, size_t ws_size,
                              hipStream_t stream) {
  (void)in_sizes; (void)n_in; (void)out_size; (void)ws_size;
  const float* x = (const float*)d_in[0];
  const float* hx = (const float*)d_in[1];
  const float* w_ih = (const float*)d_in[2];
  const float* w_hh = (const float*)d_in[3];
  const float* b_ih = (const float*)d_in[4];
  const float* b_hh = (const float*)d_in[5];
  float* out = (float*)d_out;
  char* ws = (char*)d_ws;

  // zero gab + flags (agent-coherent); rings are flag-gated
  (void)hipMemsetAsync(d_ws, 0, 8192, stream);
  pre0_gemm<<<dim3(2048), dim3(256), 0, stream>>>(x, w_ih, b_ih, b_hh, out);
  rnn_pers<<<dim3(128), dim3(256), 0, stream>>>(x, hx, w_ih, w_hh, b_ih, b_hh, out, ws);
}